// Round 9
// baseline (142.603 us; speedup 1.0000x reference)
//
#include <hip/hip_runtime.h>
#include <math.h>

constexpr int Bn = 8, Cn = 512, Sn = 256, Mn = 200, Ln = 100;

// workspace layout (floats) — ~10.8 MB
constexpr size_t OFF_V    = 0;                                 // [B][C][S]
constexpr size_t OFF_ZN   = OFF_V    + (size_t)Bn*Cn*Sn;       // [B][M][S] normalized z
constexpr size_t OFF_ZNT  = OFF_ZN   + (size_t)Bn*Mn*Sn;       // [B][S][M] zn transposed
constexpr size_t OFF_P2   = OFF_ZNT  + (size_t)Bn*Sn*Mn;       // [B][C][M] softmax_d(v.phi)
constexpr size_t OFF_ZW   = OFF_P2   + (size_t)Bn*Cn*Mn;       // [B][M]  z.wsum
constexpr size_t OFF_ZPW  = OFF_ZW   + (size_t)Bn*Mn;          // [B][M]  propagated.wsum
constexpr size_t OFF_VSUM = OFF_ZPW  + (size_t)Bn*Mn;          // [B][C]  sum_s v
constexpr size_t OFF_WSUM = OFF_VSUM + (size_t)Bn*Cn;          // [S]     row-sums of out_w

// ---------- vectorized block reductions (NW = waves per block) ----------
template<int NW>
__device__ __forceinline__ float4 blk_max_f4(float4 x, float4* red) {
  #pragma unroll
  for (int o = 32; o; o >>= 1) {
    x.x = fmaxf(x.x, __shfl_xor(x.x, o));
    x.y = fmaxf(x.y, __shfl_xor(x.y, o));
    x.z = fmaxf(x.z, __shfl_xor(x.z, o));
    x.w = fmaxf(x.w, __shfl_xor(x.w, o));
  }
  __syncthreads();
  if ((threadIdx.x & 63) == 0) red[threadIdx.x >> 6] = x;
  __syncthreads();
  float4 r = red[0];
  #pragma unroll
  for (int w = 1; w < NW; ++w) {
    r.x = fmaxf(r.x, red[w].x); r.y = fmaxf(r.y, red[w].y);
    r.z = fmaxf(r.z, red[w].z); r.w = fmaxf(r.w, red[w].w);
  }
  return r;
}
template<int NW>
__device__ __forceinline__ float4 blk_sum_f4(float4 x, float4* red) {
  #pragma unroll
  for (int o = 32; o; o >>= 1) {
    x.x += __shfl_xor(x.x, o); x.y += __shfl_xor(x.y, o);
    x.z += __shfl_xor(x.z, o); x.w += __shfl_xor(x.w, o);
  }
  __syncthreads();
  if ((threadIdx.x & 63) == 0) red[threadIdx.x >> 6] = x;
  __syncthreads();
  float4 r = red[0];
  #pragma unroll
  for (int w = 1; w < NW; ++w) {
    r.x += red[w].x; r.y += red[w].y; r.z += red[w].z; r.w += red[w].w;
  }
  return r;
}

// ---------- D1: R2-proven pool: 8x8 block-mean, 1 plane/block + wsum ----------
__global__ void __launch_bounds__(256) k_pool(const float* __restrict__ x,
                                              const float* __restrict__ ow,
                                              float* __restrict__ ws) {
  int t = threadIdx.x;
  if (blockIdx.x == 4096) {                  // wsum[s] = sum_t out_w[s,t]
    const float* row = ow + (size_t)t * Sn;
    float s = 0.f;
    for (int j = 0; j < Sn; j += 4) {
      float4 f = *(const float4*)(row + j);
      s += f.x + f.y + f.z + f.w;
    }
    ws[OFF_WSUM + t] = s;
    return;
  }
  int bc = blockIdx.x;                       // (b,c) plane, 0..4095
  const float* plane = x + (size_t)bc * 16384;
  float part[16];
  #pragma unroll
  for (int i = 0; i < 16; ++i) {
    float4 f = *(const float4*)(plane + i * 1024 + t * 4);
    part[i] = f.x + f.y + f.z + f.w;
  }
  __shared__ float lds[256][17];
  #pragma unroll
  for (int i = 0; i < 16; ++i) lds[t][i] = part[i];
  __syncthreads();
  int i = t >> 4, jj = t & 15;
  float s = 0.f;
  #pragma unroll
  for (int r = 0; r < 8; ++r)
    s += lds[32 * r + 2 * jj][i] + lds[32 * r + 2 * jj + 1][i];
  ws[OFF_V + (size_t)bc * 256 + t] = s * (1.0f / 64.0f);
}

// ---------- D2 (512 thr): blocks 0..399 = psz ; 400..911 = P2 + vsum ----------
struct PszS { float pc[4][256]; float As[4][512]; float zpart[2][4][256]; };
struct P2S  { float vl[8][256]; float t2p[2][16][104]; };
union MidS { PszS z; P2S p; };

__global__ void __launch_bounds__(512) k_mid(const float* __restrict__ psi,
                                             const float* __restrict__ phi,
                                             float* __restrict__ ws) {
  __shared__ MidS sh;
  __shared__ float4 red4[8];
  int bl = blockIdx.x, t = threadIdx.x;

  if (bl < 400) {
    // ===== psz (R2-proven 512-thr shape): t1 = v.psi -> softmax_c -> A(LDS)
    //       -> z (s-half split) -> zn/znT/zw
    int b = bl / 50, g = bl % 50, m0 = g * 4;
    const float* v = ws + OFF_V + (size_t)b * Cn * Sn;
    for (int e = t; e < 4 * 256; e += 512) {
      int mm = e >> 8, s = e & 255;
      int m = m0 + mm, k = m / Ln, d = m % Ln;
      sh.z.pc[mm][s] = psi[(size_t)k * Sn * Ln + (size_t)s * Ln + d];
    }
    __syncthreads();
    // phase 1: thread t owns channel c = t (exactly 512)
    float acc[4] = {0, 0, 0, 0};
    const float* vp = v + (size_t)t * Sn;
    for (int s = 0; s < Sn; s += 4) {
      float4 vv = *(const float4*)(vp + s);
      #pragma unroll
      for (int mm = 0; mm < 4; ++mm) {
        float4 p = *(const float4*)&sh.z.pc[mm][s];
        acc[mm] += vv.x * p.x + vv.y * p.y + vv.z * p.z + vv.w * p.w;
      }
    }
    {
      float4 a = make_float4(acc[0], acc[1], acc[2], acc[3]);
      float4 mx = blk_max_f4<8>(a, red4);
      float4 e;
      e.x = expf(a.x - mx.x); e.y = expf(a.y - mx.y);
      e.z = expf(a.z - mx.z); e.w = expf(a.w - mx.w);
      float4 se = blk_sum_f4<8>(e, red4);
      sh.z.As[0][t] = e.x / se.x;
      sh.z.As[1][t] = e.y / se.y;
      sh.z.As[2][t] = e.z / se.z;
      sh.z.As[3][t] = e.w / se.w;
    }
    __syncthreads();
    // phase 2: thread = (h = c-half, s2); 64-iter chains
    int h = t >> 8, s2 = t & 255;
    float a2[4] = {0, 0, 0, 0};
    const float* vb = v + (size_t)h * 256 * Sn;
    for (int c = 0; c < 256; c += 4) {
      float w0 = vb[(size_t)(c + 0) * Sn + s2];
      float w1 = vb[(size_t)(c + 1) * Sn + s2];
      float w2 = vb[(size_t)(c + 2) * Sn + s2];
      float w3 = vb[(size_t)(c + 3) * Sn + s2];
      #pragma unroll
      for (int mm = 0; mm < 4; ++mm) {
        float4 aa = *(const float4*)&sh.z.As[mm][h * 256 + c];
        a2[mm] += aa.x * w0 + aa.y * w1 + aa.z * w2 + aa.w * w3;
      }
    }
    #pragma unroll
    for (int mm = 0; mm < 4; ++mm) sh.z.zpart[h][mm][s2] = a2[mm];
    __syncthreads();
    float zv[4] = {0, 0, 0, 0};
    float wsv = 0.f;
    if (t < 256) {
      wsv = ws[OFF_WSUM + t];
      #pragma unroll
      for (int mm = 0; mm < 4; ++mm)
        zv[mm] = sh.z.zpart[0][mm][t] + sh.z.zpart[1][mm][t];
    }
    float4 n2 = blk_sum_f4<8>(make_float4(zv[0]*zv[0], zv[1]*zv[1],
                                          zv[2]*zv[2], zv[3]*zv[3]), red4);
    float4 zw = blk_sum_f4<8>(make_float4(zv[0]*wsv, zv[1]*wsv,
                                          zv[2]*wsv, zv[3]*wsv), red4);
    if (t < 256) {
      float zn0 = zv[0] * (1.0f / (sqrtf(n2.x) + 1e-6f));
      float zn1 = zv[1] * (1.0f / (sqrtf(n2.y) + 1e-6f));
      float zn2 = zv[2] * (1.0f / (sqrtf(n2.z) + 1e-6f));
      float zn3 = zv[3] * (1.0f / (sqrtf(n2.w) + 1e-6f));
      float* zo = ws + OFF_ZN + ((size_t)b * Mn + m0) * Sn;
      zo[0 * Sn + t] = zn0; zo[1 * Sn + t] = zn1;
      zo[2 * Sn + t] = zn2; zo[3 * Sn + t] = zn3;
      *(float4*)&ws[OFF_ZNT + ((size_t)b * Sn + t) * Mn + m0] =
          make_float4(zn0, zn1, zn2, zn3);
    }
    if (t == 0) {
      float* zwp = ws + OFF_ZW + (size_t)b * Mn + m0;
      zwp[0] = zw.x; zwp[1] = zw.y; zwp[2] = zw.z; zwp[3] = zw.w;
    }
  } else {
    // ===== P2: t2 = v.phi (s-half split) -> softmax_d -> P2 ; also vsum
    int bl2 = bl - 400;
    int b = bl2 >> 6, cgrp = bl2 & 63, c0 = cgrp * 8;
    const float* v = ws + OFF_V + ((size_t)b * Cn + c0) * Sn;
    for (int e = t; e < 8 * 256; e += 512) {
      int cc = e >> 8, s = e & 255;
      sh.p.vl[cc][s] = v[(size_t)cc * Sn + s];
    }
    __syncthreads();
    int h = t >> 8, r = t & 255;
    int k = r >> 7, d = r & 127;
    int dd = d < Ln ? d : Ln - 1;
    const float* pp = phi + (size_t)k * Sn * Ln + dd;
    float acc[8] = {0, 0, 0, 0, 0, 0, 0, 0};
    int sbase = h * 128;
    for (int si = 0; si < 128; si += 4) {          // 32-iter chains
      int s = sbase + si;
      float p0 = pp[(size_t)(s + 0) * Ln];
      float p1 = pp[(size_t)(s + 1) * Ln];
      float p2 = pp[(size_t)(s + 2) * Ln];
      float p3 = pp[(size_t)(s + 3) * Ln];
      #pragma unroll
      for (int cc = 0; cc < 8; ++cc) {
        float4 vv = *(const float4*)&sh.p.vl[cc][s];
        acc[cc] += vv.x * p0 + vv.y * p1 + vv.z * p2 + vv.w * p3;
      }
    }
    if (d < Ln) {
      #pragma unroll
      for (int cc = 0; cc < 8; ++cc) sh.p.t2p[h][k * 8 + cc][d] = acc[cc];
    }
    __syncthreads();
    // combine halves into t2p[0]
    for (int e = t; e < 16 * 104; e += 512) {
      int row = e / 104, dq = e % 104;
      if (dq < Ln) sh.p.t2p[0][row][dq] += sh.p.t2p[1][row][dq];
    }
    __syncthreads();
    if (t < 256) {
      int gg = t >> 4, l = t & 15;
      int k2 = gg >> 3, cc2 = gg & 7;
      float mx = -1e30f;
      for (int dq = l; dq < Ln; dq += 16) mx = fmaxf(mx, sh.p.t2p[0][gg][dq]);
      #pragma unroll
      for (int o = 8; o; o >>= 1) mx = fmaxf(mx, __shfl_xor(mx, o));
      float se = 0.f;
      for (int dq = l; dq < Ln; dq += 16) se += expf(sh.p.t2p[0][gg][dq] - mx);
      #pragma unroll
      for (int o = 8; o; o >>= 1) se += __shfl_xor(se, o);
      float* p2row = ws + OFF_P2 + ((size_t)b * Cn + c0 + cc2) * Mn + k2 * Ln;
      for (int dq = l; dq < Ln; dq += 16)
        p2row[dq] = expf(sh.p.t2p[0][gg][dq] - mx) / se;
      if (k2 == 0) {                        // vsum[c] = sum_s v[c,s]
        float vs = 0.f;
        for (int i2 = 0; i2 < 16; ++i2) vs += sh.p.vl[cc2][i2 * 16 + l];
        #pragma unroll
        for (int o = 8; o; o >>= 1) vs += __shfl_xor(vs, o);
        if (l == 0) ws[OFF_VSUM + (size_t)b * Cn + c0 + cc2] = vs;
      }
    }
  }
}

// ---------- D3 (512 thr): Gram softmax rows -> zp_w ; 400 blocks ----------
__global__ void __launch_bounds__(512) k_gram(float* __restrict__ ws) {
  int bl = blockIdx.x, t = threadIdx.x;
  int b = bl / 50, g = bl % 50, m0 = g * 4;
  __shared__ __align__(16) float zl[4][256];
  __shared__ float zwl[200];
  __shared__ float4 dotp[2][256];
  __shared__ float4 red4[8];
  const float* zn  = ws + OFF_ZN  + (size_t)b * Mn * Sn;
  const float* znT = ws + OFF_ZNT + (size_t)b * Sn * Mn;
  for (int e = t; e < 4 * 256; e += 512) {
    int mm = e >> 8, s = e & 255;
    zl[mm][s] = zn[(size_t)(m0 + mm) * Sn + s];
  }
  if (t < Mn) zwl[t] = ws[OFF_ZW + (size_t)b * Mn + t];
  __syncthreads();
  int h = t >> 8, n = t & 255;
  bool act = n < Mn;
  float dot[4] = {0, 0, 0, 0};
  if (act) {
    const float* zc = znT + n;               // column n, coalesced across lanes
    int sbase = h * 128;
    for (int si = 0; si < 128; si += 4) {    // 32-iter chains
      int s = sbase + si;
      float c0v = zc[(size_t)(s + 0) * Mn], c1v = zc[(size_t)(s + 1) * Mn];
      float c2v = zc[(size_t)(s + 2) * Mn], c3v = zc[(size_t)(s + 3) * Mn];
      #pragma unroll
      for (int mm = 0; mm < 4; ++mm) {
        float4 za = *(const float4*)&zl[mm][s];
        dot[mm] += za.x * c0v + za.y * c1v + za.z * c2v + za.w * c3v;
      }
    }
  }
  dotp[h][n] = make_float4(dot[0], dot[1], dot[2], dot[3]);
  __syncthreads();
  float4 e = make_float4(0.f, 0.f, 0.f, 0.f);
  float zwn = 0.f;
  if (t < 256 && t < Mn) {
    float4 d0 = dotp[0][t], d1 = dotp[1][t];
    // |zn.zn| <= 1 -> exp stable without max-subtract
    e.x = expf(d0.x + d1.x); e.y = expf(d0.y + d1.y);
    e.z = expf(d0.z + d1.z); e.w = expf(d0.w + d1.w);
    zwn = zwl[t];
  }
  float4 se = blk_sum_f4<8>(e, red4);
  float4 sez = blk_sum_f4<8>(make_float4(e.x*zwn, e.y*zwn, e.z*zwn, e.w*zwn), red4);
  if (t == 0) {
    float* zp = ws + OFF_ZPW + (size_t)b * Mn + m0;
    zp[0] = sez.x / se.x; zp[1] = sez.y / se.y;
    zp[2] = sez.z / se.z; zp[3] = sez.w / se.w;
  }
}

// ---------- D4: out[b,c] = sigmoid((vsum + P2[c,:].zp_w)/256) ; 512 blocks ----------
__global__ void __launch_bounds__(256) k_dot(float* __restrict__ ws,
                                             float* __restrict__ out) {
  int bl = blockIdx.x, t = threadIdx.x;
  int b = bl >> 6, cg = bl & 63, c0 = cg * 8;
  __shared__ float zpl[200];
  if (t < Mn) zpl[t] = ws[OFF_ZPW + (size_t)b * Mn + t];
  __syncthreads();
  int c = c0 + (t >> 5), l = t & 31;
  const float* p2 = ws + OFF_P2 + ((size_t)b * Cn + c) * Mn;
  float acc = 0.f;
  for (int m = l; m < Mn; m += 32) acc += p2[m] * zpl[m];   // 128B coalesced
  #pragma unroll
  for (int o = 16; o; o >>= 1) acc += __shfl_xor(acc, o);
  if (l == 0) {
    float f = (ws[OFF_VSUM + (size_t)b * Cn + c] + acc) * (1.0f / 256.0f);
    out[(size_t)b * Cn + c] = 1.0f / (1.0f + expf(-f));
  }
}

extern "C" void kernel_launch(void* const* d_in, const int* in_sizes, int n_in,
                              void* d_out, int out_size, void* d_ws, size_t ws_size,
                              hipStream_t stream) {
  const float* x   = (const float*)d_in[0];
  const float* psi = (const float*)d_in[1];
  const float* phi = (const float*)d_in[2];
  const float* ow  = (const float*)d_in[3];
  float* out = (float*)d_out;
  float* ws  = (float*)d_ws;

  hipLaunchKernelGGL(k_pool, dim3(4097), dim3(256), 0, stream, x, ow, ws);
  hipLaunchKernelGGL(k_mid,  dim3(912),  dim3(512), 0, stream, psi, phi, ws);
  hipLaunchKernelGGL(k_gram, dim3(400),  dim3(512), 0, stream, ws);
  hipLaunchKernelGGL(k_dot,  dim3(512),  dim3(256), 0, stream, ws, out);
}